// Round 11
// baseline (284.420 us; speedup 1.0000x reference)
//
#include <hip/hip_runtime.h>
#include <hip/hip_fp16.h>
#include <math.h>

// ---------------------------------------------------------------------------
// GAT 2-layer forward, N=50000, E=800000 (+N self loops), EMB=128,
// layer1: heads=8, C=16 (concat -> 128), layer2: heads=1, C=64.
// CSR-by-dst build per call, one gather pass per layer, softmax without
// max-subtraction. h1/h2/act1 fp16. GEMMs on MFMA with augmented-weight alpha
// fusion (R9). Padded cursor atomics (R10).
// R11: (a) 8-copy histogram deg8[n*8+xcd] -- each XCD increments only its own
//      copy, atomic lines never migrate between XCDs; scan1 sums the copies.
//      (b) agg1/agg2 node ranges bucketed by blockIdx&7 to match scatter's
//      dst-bucketing -> esrc/rowstart slices are XCD-L2-local.
// ---------------------------------------------------------------------------

typedef _Float16 f16x8 __attribute__((ext_vector_type(8)));
typedef float f32x4 __attribute__((ext_vector_type(4)));

#define PAD 16  // ints per cursor slot (64B line)

// 8-copy histogram: copy c = blockIdx&7; deg8[n*8+c]. A 64B line holds the 8
// copies of 2 nodes; each copy is touched by exactly one XCD (round-robin
// block dispatch) -> no cross-XCD line migration.
__global__ __launch_bounds__(256) void hist_kernel(const int* __restrict__ dst, int E,
                                                   int* __restrict__ deg8) {
    int c = blockIdx.x & 7;
    int i = (blockIdx.x * 256 + threadIdx.x) * 4;
    if (i + 3 < E) {
        int4 d = *(const int4*)(dst + i);
        atomicAdd(&deg8[d.x * 8 + c], 1);
        atomicAdd(&deg8[d.y * 8 + c], 1);
        atomicAdd(&deg8[d.z * 8 + c], 1);
        atomicAdd(&deg8[d.w * 8 + c], 1);
    } else {
        for (int k = i; k < E; k++) atomicAdd(&deg8[dst[k] * 8 + c], 1);
    }
}

__global__ __launch_bounds__(256) void scan1_kernel(const int* __restrict__ deg8, int N,
                                                    int* __restrict__ rowstart,
                                                    int* __restrict__ blocksum) {
    __shared__ int tmp[256];
    int t = threadIdx.x;
    int i = blockIdx.x * 256 + t;
    int v = 0;
    if (i < N) {
        int4 a = *(const int4*)(deg8 + i * 8);
        int4 b = *(const int4*)(deg8 + i * 8 + 4);
        v = a.x + a.y + a.z + a.w + b.x + b.y + b.z + b.w;
    }
    tmp[t] = v;
    __syncthreads();
    for (int off = 1; off < 256; off <<= 1) {
        int x = (t >= off) ? tmp[t - off] : 0;
        __syncthreads();
        tmp[t] += x;
        __syncthreads();
    }
    if (i < N) rowstart[i] = tmp[t] - v;
    if (t == 255) blocksum[blockIdx.x] = tmp[t];
}

__global__ __launch_bounds__(256) void scan23_kernel(int* __restrict__ rowstart,
                                                     const int* __restrict__ blocksum,
                                                     int nb,
                                                     int* __restrict__ cursor,
                                                     int N, int E) {
    __shared__ int sdata[256];
    int t = threadIdx.x;
    int b = blockIdx.x;
    sdata[t] = (t < nb && t < b) ? blocksum[t] : 0;
    __syncthreads();
#pragma unroll
    for (int off = 128; off > 0; off >>= 1) {
        if (t < off) sdata[t] += sdata[t + off];
        __syncthreads();
    }
    int offset = sdata[0];
    int i = b * 256 + t;
    if (i < N) {
        int v = rowstart[i] + offset;
        rowstart[i] = v;
        cursor[i * PAD] = v;
    } else if (i == N) {
        rowstart[N] = E;
    }
}

// Bucketed scatter: block (blockIdx&7) commits only dst in its 1/8 range of
// nodes -> esrc write lines + cursor lines stay within one XCD's L2.
__global__ __launch_bounds__(256) void scatter_kernel(const int* __restrict__ src,
                                                      const int* __restrict__ dst,
                                                      int E, int N,
                                                      int* __restrict__ cursor,
                                                      int* __restrict__ esrc) {
    int b = blockIdx.x & 7;
    int chunk = blockIdx.x >> 3;
    int bdiv = (N + 7) >> 3;
    int blo = b * bdiv;
    int bhi = blo + bdiv;
    int base = chunk * 1024 + threadIdx.x;
#pragma unroll
    for (int u = 0; u < 4; u++) {
        int i = base + u * 256;
        if (i < E) {
            int d = dst[i];
            int s = src[i];
            if (d >= blo && d < bhi) {
                int p = atomicAdd(&cursor[d * PAD], 1);
                esrc[p] = s;
            }
        }
    }
}

// Prep: build transposed fp16 augmented weights.
__global__ __launch_bounds__(256) void augw_kernel(const float* __restrict__ W1,
                                                   const float* __restrict__ a1s,
                                                   const float* __restrict__ a1d,
                                                   const float* __restrict__ W2,
                                                   const float* __restrict__ a2s,
                                                   const float* __restrict__ a2d,
                                                   _Float16* __restrict__ W1t,
                                                   _Float16* __restrict__ W2t) {
    int t = threadIdx.x;
    if (blockIdx.x == 0) {
        for (int i = t; i < 144 * 128; i += 256) {
            int c = i >> 7, k = i & 127;
            float v;
            if (c < 128) {
                v = W1[k * 128 + c];
            } else if (c < 136) {
                int h = c - 128; v = 0.f;
#pragma unroll
                for (int j = 0; j < 16; j++) v += W1[k * 128 + h * 16 + j] * a1s[h * 16 + j];
            } else {
                int h = c - 136; v = 0.f;
#pragma unroll
                for (int j = 0; j < 16; j++) v += W1[k * 128 + h * 16 + j] * a1d[h * 16 + j];
            }
            W1t[c * 128 + k] = (_Float16)v;
        }
    } else {
        for (int i = t; i < 80 * 128; i += 256) {
            int c = i >> 7, k = i & 127;
            float v = 0.f;
            if (c < 64) {
                v = W2[k * 64 + c];
            } else if (c == 64) {
                for (int j = 0; j < 64; j++) v += W2[k * 64 + j] * a2s[j];
            } else if (c == 65) {
                for (int j = 0; j < 64; j++) v += W2[k * 64 + j] * a2d[j];
            }
            W2t[c * 128 + k] = (_Float16)v;
        }
    }
}

// MFMA GEMM1: 64 rows x 144 cols per block (4 waves x 16 rows, 9 col-frags).
// x staged fp32->fp16 into LDS; W1t B-frags from global (36KB, L1-resident).
__global__ __launch_bounds__(256) void gemm1_kernel(const float* __restrict__ x,
                                                    const _Float16* __restrict__ W1t,
                                                    __half* __restrict__ h1,
                                                    float* __restrict__ als,
                                                    float* __restrict__ ald, int N) {
    __shared__ _Float16 Xs[64 * 136];  // 17 KB
    int t = threadIdx.x;
    int row0 = blockIdx.x * 64;
    for (int i = t; i < 2048; i += 256) {
        int r = i >> 5, c4 = i & 31;
        int gr = row0 + r;
        float4 v = make_float4(0.f, 0.f, 0.f, 0.f);
        if (gr < N) v = *(const float4*)(x + (size_t)gr * 128 + c4 * 4);
        _Float16* dp = Xs + r * 136 + c4 * 4;
        dp[0] = (_Float16)v.x; dp[1] = (_Float16)v.y;
        dp[2] = (_Float16)v.z; dp[3] = (_Float16)v.w;
    }
    __syncthreads();
    int w = t >> 6, L = t & 63, m = L & 15, quad = L >> 4;
    f32x4 acc[9];
#pragma unroll
    for (int f = 0; f < 9; f++) acc[f] = (f32x4){0.f, 0.f, 0.f, 0.f};
    const _Float16* Arow = Xs + (w * 16 + m) * 136 + quad * 8;
    const _Float16* Brow = W1t + m * 128 + quad * 8;
#pragma unroll
    for (int kt = 0; kt < 4; kt++) {
        f16x8 a = *(const f16x8*)(Arow + kt * 32);
#pragma unroll
        for (int f = 0; f < 9; f++) {
            f16x8 b = *(const f16x8*)(Brow + f * 2048 + kt * 32);
            acc[f] = __builtin_amdgcn_mfma_f32_16x16x32_f16(a, b, acc[f], 0, 0, 0);
        }
    }
    int nbase = row0 + w * 16 + quad * 4;
#pragma unroll
    for (int r = 0; r < 4; r++) {
        int n = nbase + r;
        if (n < N) {
            __half* hrow = h1 + (size_t)n * 128 + m;
#pragma unroll
            for (int f = 0; f < 8; f++) hrow[f * 16] = __float2half(acc[f][r]);
            float v = acc[8][r];
            if (m < 8) als[n * 8 + m] = v;
            else ald[n * 8 + (m - 8)] = v;
        }
    }
}

// Aggregation layer 1, node-per-group, XCD-bucketed: bucket = blockIdx&7
// (matches scatter's dst ranges -> esrc/rowstart slices XCD-L2-local).
// Wave = 8 nodes x 8 lanes; lane q owns head q's 16 channels.
__global__ __launch_bounds__(256) void agg1_kernel(const __half* __restrict__ h1,
                                                   const float* __restrict__ als,
                                                   const float* __restrict__ ald,
                                                   const int* __restrict__ rowstart,
                                                   const int* __restrict__ esrc,
                                                   const float* __restrict__ b1,
                                                   __half* __restrict__ act1, int N) {
    int t = threadIdx.x;
    int lane = t & 63;
    int grp = lane >> 3;
    int q = lane & 7;
    int bdiv = (N + 7) >> 3;
    int ln = (blockIdx.x >> 3) * 32 + (t >> 6) * 8 + grp;
    if (ln >= bdiv) return;
    int n = (blockIdx.x & 7) * bdiv + ln;
    if (n >= N) return;
    const float4* h1v = (const float4*)h1;
    float adv = ald[n * 8 + q];
    float acc[16];
    float wsum;
    {  // self loop
        float e = als[n * 8 + q] + adv;
        e = (e > 0.f) ? e : 0.2f * e;
        float w = __expf(e);
        wsum = w;
        float4 hv0 = h1v[(size_t)n * 16 + 2 * q];
        float4 hv1 = h1v[(size_t)n * 16 + 2 * q + 1];
        const __half2* p0 = (const __half2*)&hv0;
        const __half2* p1 = (const __half2*)&hv1;
#pragma unroll
        for (int k = 0; k < 4; k++) {
            float2 f = __half22float2(p0[k]);
            acc[2 * k] = w * f.x;
            acc[2 * k + 1] = w * f.y;
        }
#pragma unroll
        for (int k = 0; k < 4; k++) {
            float2 f = __half22float2(p1[k]);
            acc[8 + 2 * k] = w * f.x;
            acc[8 + 2 * k + 1] = w * f.y;
        }
    }
    int beg = rowstart[n], end = rowstart[n + 1];
    for (int j = beg; j < end; j++) {
        int s = esrc[j];
        float e = als[s * 8 + q] + adv;
        e = (e > 0.f) ? e : 0.2f * e;
        float w = __expf(e);
        wsum += w;
        float4 hv0 = h1v[(size_t)s * 16 + 2 * q];
        float4 hv1 = h1v[(size_t)s * 16 + 2 * q + 1];
        const __half2* p0 = (const __half2*)&hv0;
        const __half2* p1 = (const __half2*)&hv1;
#pragma unroll
        for (int k = 0; k < 4; k++) {
            float2 f = __half22float2(p0[k]);
            acc[2 * k] += w * f.x;
            acc[2 * k + 1] += w * f.y;
        }
#pragma unroll
        for (int k = 0; k < 4; k++) {
            float2 f = __half22float2(p1[k]);
            acc[8 + 2 * k] += w * f.x;
            acc[8 + 2 * k + 1] += w * f.y;
        }
    }
    float inv = 1.f / (wsum + 1e-16f);
    const float* bf = b1 + q * 16;
    __align__(16) __half2 po[8];
#pragma unroll
    for (int k = 0; k < 8; k++) {
        float o0 = acc[2 * k] * inv + bf[2 * k];
        float o1 = acc[2 * k + 1] * inv + bf[2 * k + 1];
        o0 = (o0 > 0.f) ? o0 : (__expf(o0) - 1.f);  // ELU
        o1 = (o1 > 0.f) ? o1 : (__expf(o1) - 1.f);
        po[k] = __floats2half2_rn(o0, o1);
    }
    float4* ov = (float4*)(act1 + (size_t)n * 128 + q * 16);
    ov[0] = ((float4*)po)[0];
    ov[1] = ((float4*)po)[1];
}

// MFMA GEMM2: 64 rows x 80 cols per block; A-frags straight from global act1
// (fp16), B-frags from W2t (20KB, L1-resident). No LDS.
__global__ __launch_bounds__(256) void gemm2_kernel(const __half* __restrict__ act1,
                                                    const _Float16* __restrict__ W2t,
                                                    __half* __restrict__ h2,
                                                    float* __restrict__ al2s,
                                                    float* __restrict__ al2d, int N) {
    int t = threadIdx.x;
    int row0 = blockIdx.x * 64;
    int w = t >> 6, L = t & 63, m = L & 15, quad = L >> 4;
    f32x4 acc[5];
#pragma unroll
    for (int f = 0; f < 5; f++) acc[f] = (f32x4){0.f, 0.f, 0.f, 0.f};
    const _Float16* Arow =
        (const _Float16*)act1 + (size_t)(row0 + w * 16 + m) * 128 + quad * 8;
    const _Float16* Brow = W2t + m * 128 + quad * 8;
#pragma unroll
    for (int kt = 0; kt < 4; kt++) {
        f16x8 a = *(const f16x8*)(Arow + kt * 32);
#pragma unroll
        for (int f = 0; f < 5; f++) {
            f16x8 b = *(const f16x8*)(Brow + f * 2048 + kt * 32);
            acc[f] = __builtin_amdgcn_mfma_f32_16x16x32_f16(a, b, acc[f], 0, 0, 0);
        }
    }
    int nbase = row0 + w * 16 + quad * 4;
#pragma unroll
    for (int r = 0; r < 4; r++) {
        int n = nbase + r;
        if (n < N) {
            __half* hrow = h2 + (size_t)n * 64 + m;
#pragma unroll
            for (int f = 0; f < 4; f++) hrow[f * 16] = __float2half(acc[f][r]);
            if (m == 0) al2s[n] = acc[4][r];
            else if (m == 1) al2d[n] = acc[4][r];
        }
    }
}

// Aggregation layer 2, node-per-group, XCD-bucketed like agg1; lane q owns
// channels 8q..8q+7.
__global__ __launch_bounds__(256) void agg2_kernel(const __half* __restrict__ h2,
                                                   const float* __restrict__ al2s,
                                                   const float* __restrict__ al2d,
                                                   const int* __restrict__ rowstart,
                                                   const int* __restrict__ esrc,
                                                   const float* __restrict__ b2,
                                                   float* __restrict__ out, int N) {
    int t = threadIdx.x;
    int lane = t & 63;
    int grp = lane >> 3;
    int q = lane & 7;
    int bdiv = (N + 7) >> 3;
    int ln = (blockIdx.x >> 3) * 32 + (t >> 6) * 8 + grp;
    if (ln >= bdiv) return;
    int n = (blockIdx.x & 7) * bdiv + ln;
    if (n >= N) return;
    const float4* h2v = (const float4*)h2;
    float adv = al2d[n];
    float acc[8];
    float wsum;
    {  // self loop
        float e = al2s[n] + adv;
        e = (e > 0.f) ? e : 0.2f * e;
        float w = __expf(e);
        wsum = w;
        float4 hv = h2v[(size_t)n * 8 + q];
        const __half2* hp = (const __half2*)&hv;
#pragma unroll
        for (int k = 0; k < 4; k++) {
            float2 f = __half22float2(hp[k]);
            acc[2 * k] = w * f.x;
            acc[2 * k + 1] = w * f.y;
        }
    }
    int beg = rowstart[n], end = rowstart[n + 1];
    for (int j = beg; j < end; j++) {
        int s = esrc[j];
        float e = al2s[s] + adv;
        e = (e > 0.f) ? e : 0.2f * e;
        float w = __expf(e);
        wsum += w;
        float4 hv = h2v[(size_t)s * 8 + q];
        const __half2* hp = (const __half2*)&hv;
#pragma unroll
        for (int k = 0; k < 4; k++) {
            float2 f = __half22float2(hp[k]);
            acc[2 * k] += w * f.x;
            acc[2 * k + 1] += w * f.y;
        }
    }
    float inv = 1.f / (wsum + 1e-16f);
    const float* bf = b2 + q * 8;
    float4* ov = (float4*)(out + (size_t)n * 64 + q * 8);
    ov[0] = make_float4(acc[0] * inv + bf[0], acc[1] * inv + bf[1],
                        acc[2] * inv + bf[2], acc[3] * inv + bf[3]);
    ov[1] = make_float4(acc[4] * inv + bf[4], acc[5] * inv + bf[5],
                        acc[6] * inv + bf[6], acc[7] * inv + bf[7]);
}

extern "C" void kernel_launch(void* const* d_in, const int* in_sizes, int n_in,
                              void* d_out, int out_size, void* d_ws, size_t ws_size,
                              hipStream_t stream) {
    (void)n_in; (void)out_size; (void)ws_size;
    const float* x   = (const float*)d_in[0];
    const int*   ei  = (const int*)d_in[1];
    const float* W1  = (const float*)d_in[2];
    const float* a1s = (const float*)d_in[3];
    const float* a1d = (const float*)d_in[4];
    const float* b1  = (const float*)d_in[5];
    const float* W2  = (const float*)d_in[6];
    const float* a2s = (const float*)d_in[7];
    const float* a2d = (const float*)d_in[8];
    const float* b2  = (const float*)d_in[9];
    float* out = (float*)d_out;

    const int N = in_sizes[0] / 128;
    const int E = in_sizes[1] / 2;
    const int* src = ei;
    const int* dst = ei + E;

    char* wp = (char*)d_ws;
    auto alloc = [&](size_t bytes) -> void* {
        void* p = (void*)wp;
        wp += (bytes + 255) & ~(size_t)255;
        return p;
    };
    __half* h1   = (__half*)alloc((size_t)N * 128 * 2);
    __half* act1 = (__half*)alloc((size_t)N * 128 * 2);
    __half* h2   = (__half*)alloc((size_t)N * 64 * 2 + 64 * 256);  // +pad for gemm2 tail
    float* al1s = (float*)alloc((size_t)N * 8 * 4);
    float* al1d = (float*)alloc((size_t)N * 8 * 4);
    float* al2s = (float*)alloc((size_t)N * 4);
    float* al2d = (float*)alloc((size_t)N * 4);
    int* deg8     = (int*)alloc((size_t)N * 8 * 4);    // 8 XCD-local copies
    int* rowstart = (int*)alloc((size_t)(N + 1) * 4);
    int* cursor   = (int*)alloc((size_t)N * PAD * 4);  // 1 counter / 64B line
    int* esrc     = (int*)alloc((size_t)E * 4);
    int* blocksum = (int*)alloc(256 * 4);
    _Float16* W1t = (_Float16*)alloc(144 * 128 * 2);
    _Float16* W2t = (_Float16*)alloc(80 * 128 * 2);

    const int nbScan = (N + 255) / 256;
    const int gridH  = (E + 1023) / 1024;
    const int gridG1 = (N + 63) / 64;
    const int gridScat = ((E + 1023) / 1024) * 8;
    const int gridG2 = (N + 63) / 64;
    const int bdiv = (N + 7) / 8;
    const int gridAggN = 8 * ((bdiv + 31) / 32);

    hipMemsetAsync(deg8, 0, (size_t)N * 8 * 4, stream);

    augw_kernel<<<2, 256, 0, stream>>>(W1, a1s, a1d, W2, a2s, a2d, W1t, W2t);
    hist_kernel<<<gridH, 256, 0, stream>>>(dst, E, deg8);
    gemm1_kernel<<<gridG1, 256, 0, stream>>>(x, W1t, h1, al1s, al1d, N);
    scan1_kernel<<<nbScan, 256, 0, stream>>>(deg8, N, rowstart, blocksum);
    scan23_kernel<<<(N + 256) / 256, 256, 0, stream>>>(rowstart, blocksum, nbScan,
                                                       cursor, N, E);
    scatter_kernel<<<gridScat, 256, 0, stream>>>(src, dst, E, N, cursor, esrc);

    agg1_kernel<<<gridAggN, 256, 0, stream>>>(h1, al1s, al1d, rowstart, esrc, b1, act1, N);
    gemm2_kernel<<<gridG2, 256, 0, stream>>>(act1, W2t, h2, al2s, al2d, N);
    agg2_kernel<<<gridAggN, 256, 0, stream>>>(h2, al2s, al2d, rowstart, esrc, b2, out, N);
}

// Round 12
// 272.100 us; speedup vs baseline: 1.0453x; 1.0453x over previous
//
#include <hip/hip_runtime.h>
#include <hip/hip_fp16.h>
#include <math.h>

// ---------------------------------------------------------------------------
// GAT 2-layer forward, N=50000, E=800000 (+N self loops), EMB=128,
// layer1: heads=8, C=16 (concat -> 128), layer2: heads=1, C=64.
// CSR-by-dst build per call, one gather pass per layer, softmax without
// max-subtraction. h1/h2/act1 fp16. MFMA GEMMs with augmented-weight alpha
// fusion (R9). 8-copy hist + padded cursor (R10/R11).
// R12: agg1/agg2 edge loops manually UNROLLED BY 4 with batched loads
//      (4 esrc + 8 h1-vec4 + 4 als issued together) -> ~4x outstanding
//      loads per lane; attacks the 44us latency plateau in agg1.
// ---------------------------------------------------------------------------

typedef _Float16 f16x8 __attribute__((ext_vector_type(8)));
typedef float f32x4 __attribute__((ext_vector_type(4)));

#define PAD 16  // ints per cursor slot (64B line)

__device__ __forceinline__ float leaky_exp(float e) {
    e = (e > 0.f) ? e : 0.2f * e;
    return __expf(e);
}

__device__ __forceinline__ void acc16(float w, float4 hv0, float4 hv1,
                                      float* __restrict__ acc) {
    const __half2* p0 = (const __half2*)&hv0;
    const __half2* p1 = (const __half2*)&hv1;
#pragma unroll
    for (int k = 0; k < 4; k++) {
        float2 f = __half22float2(p0[k]);
        acc[2 * k] += w * f.x;
        acc[2 * k + 1] += w * f.y;
    }
#pragma unroll
    for (int k = 0; k < 4; k++) {
        float2 f = __half22float2(p1[k]);
        acc[8 + 2 * k] += w * f.x;
        acc[8 + 2 * k + 1] += w * f.y;
    }
}

__device__ __forceinline__ void acc8(float w, float4 hv,
                                     float* __restrict__ acc) {
    const __half2* hp = (const __half2*)&hv;
#pragma unroll
    for (int k = 0; k < 4; k++) {
        float2 f = __half22float2(hp[k]);
        acc[2 * k] += w * f.x;
        acc[2 * k + 1] += w * f.y;
    }
}

// 8-copy histogram: copy c = blockIdx&7 -> per-XCD atomic lines.
__global__ __launch_bounds__(256) void hist_kernel(const int* __restrict__ dst, int E,
                                                   int* __restrict__ deg8) {
    int c = blockIdx.x & 7;
    int i = (blockIdx.x * 256 + threadIdx.x) * 4;
    if (i + 3 < E) {
        int4 d = *(const int4*)(dst + i);
        atomicAdd(&deg8[d.x * 8 + c], 1);
        atomicAdd(&deg8[d.y * 8 + c], 1);
        atomicAdd(&deg8[d.z * 8 + c], 1);
        atomicAdd(&deg8[d.w * 8 + c], 1);
    } else {
        for (int k = i; k < E; k++) atomicAdd(&deg8[dst[k] * 8 + c], 1);
    }
}

__global__ __launch_bounds__(256) void scan1_kernel(const int* __restrict__ deg8, int N,
                                                    int* __restrict__ rowstart,
                                                    int* __restrict__ blocksum) {
    __shared__ int tmp[256];
    int t = threadIdx.x;
    int i = blockIdx.x * 256 + t;
    int v = 0;
    if (i < N) {
        int4 a = *(const int4*)(deg8 + i * 8);
        int4 b = *(const int4*)(deg8 + i * 8 + 4);
        v = a.x + a.y + a.z + a.w + b.x + b.y + b.z + b.w;
    }
    tmp[t] = v;
    __syncthreads();
    for (int off = 1; off < 256; off <<= 1) {
        int x = (t >= off) ? tmp[t - off] : 0;
        __syncthreads();
        tmp[t] += x;
        __syncthreads();
    }
    if (i < N) rowstart[i] = tmp[t] - v;
    if (t == 255) blocksum[blockIdx.x] = tmp[t];
}

__global__ __launch_bounds__(256) void scan23_kernel(int* __restrict__ rowstart,
                                                     const int* __restrict__ blocksum,
                                                     int nb,
                                                     int* __restrict__ cursor,
                                                     int N, int E) {
    __shared__ int sdata[256];
    int t = threadIdx.x;
    int b = blockIdx.x;
    sdata[t] = (t < nb && t < b) ? blocksum[t] : 0;
    __syncthreads();
#pragma unroll
    for (int off = 128; off > 0; off >>= 1) {
        if (t < off) sdata[t] += sdata[t + off];
        __syncthreads();
    }
    int offset = sdata[0];
    int i = b * 256 + t;
    if (i < N) {
        int v = rowstart[i] + offset;
        rowstart[i] = v;
        cursor[i * PAD] = v;
    } else if (i == N) {
        rowstart[N] = E;
    }
}

// Bucketed scatter: block (blockIdx&7) commits only dst in its 1/8 range.
__global__ __launch_bounds__(256) void scatter_kernel(const int* __restrict__ src,
                                                      const int* __restrict__ dst,
                                                      int E, int N,
                                                      int* __restrict__ cursor,
                                                      int* __restrict__ esrc) {
    int b = blockIdx.x & 7;
    int chunk = blockIdx.x >> 3;
    int bdiv = (N + 7) >> 3;
    int blo = b * bdiv;
    int bhi = blo + bdiv;
    int base = chunk * 1024 + threadIdx.x;
#pragma unroll
    for (int u = 0; u < 4; u++) {
        int i = base + u * 256;
        if (i < E) {
            int d = dst[i];
            int s = src[i];
            if (d >= blo && d < bhi) {
                int p = atomicAdd(&cursor[d * PAD], 1);
                esrc[p] = s;
            }
        }
    }
}

// Prep: build transposed fp16 augmented weights.
__global__ __launch_bounds__(256) void augw_kernel(const float* __restrict__ W1,
                                                   const float* __restrict__ a1s,
                                                   const float* __restrict__ a1d,
                                                   const float* __restrict__ W2,
                                                   const float* __restrict__ a2s,
                                                   const float* __restrict__ a2d,
                                                   _Float16* __restrict__ W1t,
                                                   _Float16* __restrict__ W2t) {
    int t = threadIdx.x;
    if (blockIdx.x == 0) {
        for (int i = t; i < 144 * 128; i += 256) {
            int c = i >> 7, k = i & 127;
            float v;
            if (c < 128) {
                v = W1[k * 128 + c];
            } else if (c < 136) {
                int h = c - 128; v = 0.f;
#pragma unroll
                for (int j = 0; j < 16; j++) v += W1[k * 128 + h * 16 + j] * a1s[h * 16 + j];
            } else {
                int h = c - 136; v = 0.f;
#pragma unroll
                for (int j = 0; j < 16; j++) v += W1[k * 128 + h * 16 + j] * a1d[h * 16 + j];
            }
            W1t[c * 128 + k] = (_Float16)v;
        }
    } else {
        for (int i = t; i < 80 * 128; i += 256) {
            int c = i >> 7, k = i & 127;
            float v = 0.f;
            if (c < 64) {
                v = W2[k * 64 + c];
            } else if (c == 64) {
                for (int j = 0; j < 64; j++) v += W2[k * 64 + j] * a2s[j];
            } else if (c == 65) {
                for (int j = 0; j < 64; j++) v += W2[k * 64 + j] * a2d[j];
            }
            W2t[c * 128 + k] = (_Float16)v;
        }
    }
}

// MFMA GEMM1: 64 rows x 144 cols per block (4 waves x 16 rows, 9 col-frags).
__global__ __launch_bounds__(256) void gemm1_kernel(const float* __restrict__ x,
                                                    const _Float16* __restrict__ W1t,
                                                    __half* __restrict__ h1,
                                                    float* __restrict__ als,
                                                    float* __restrict__ ald, int N) {
    __shared__ _Float16 Xs[64 * 136];  // 17 KB
    int t = threadIdx.x;
    int row0 = blockIdx.x * 64;
    for (int i = t; i < 2048; i += 256) {
        int r = i >> 5, c4 = i & 31;
        int gr = row0 + r;
        float4 v = make_float4(0.f, 0.f, 0.f, 0.f);
        if (gr < N) v = *(const float4*)(x + (size_t)gr * 128 + c4 * 4);
        _Float16* dp = Xs + r * 136 + c4 * 4;
        dp[0] = (_Float16)v.x; dp[1] = (_Float16)v.y;
        dp[2] = (_Float16)v.z; dp[3] = (_Float16)v.w;
    }
    __syncthreads();
    int w = t >> 6, L = t & 63, m = L & 15, quad = L >> 4;
    f32x4 acc[9];
#pragma unroll
    for (int f = 0; f < 9; f++) acc[f] = (f32x4){0.f, 0.f, 0.f, 0.f};
    const _Float16* Arow = Xs + (w * 16 + m) * 136 + quad * 8;
    const _Float16* Brow = W1t + m * 128 + quad * 8;
#pragma unroll
    for (int kt = 0; kt < 4; kt++) {
        f16x8 a = *(const f16x8*)(Arow + kt * 32);
#pragma unroll
        for (int f = 0; f < 9; f++) {
            f16x8 b = *(const f16x8*)(Brow + f * 2048 + kt * 32);
            acc[f] = __builtin_amdgcn_mfma_f32_16x16x32_f16(a, b, acc[f], 0, 0, 0);
        }
    }
    int nbase = row0 + w * 16 + quad * 4;
#pragma unroll
    for (int r = 0; r < 4; r++) {
        int n = nbase + r;
        if (n < N) {
            __half* hrow = h1 + (size_t)n * 128 + m;
#pragma unroll
            for (int f = 0; f < 8; f++) hrow[f * 16] = __float2half(acc[f][r]);
            float v = acc[8][r];
            if (m < 8) als[n * 8 + m] = v;
            else ald[n * 8 + (m - 8)] = v;
        }
    }
}

// Aggregation layer 1, node-per-group (8 nodes/wave x 8 lanes, lane q = head
// q's 16 channels), XCD-bucketed; edge loop UNROLLED x4 with batched loads.
__global__ __launch_bounds__(256) void agg1_kernel(const __half* __restrict__ h1,
                                                   const float* __restrict__ als,
                                                   const float* __restrict__ ald,
                                                   const int* __restrict__ rowstart,
                                                   const int* __restrict__ esrc,
                                                   const float* __restrict__ b1,
                                                   __half* __restrict__ act1, int N) {
    int t = threadIdx.x;
    int lane = t & 63;
    int grp = lane >> 3;
    int q = lane & 7;
    int bdiv = (N + 7) >> 3;
    int ln = (blockIdx.x >> 3) * 32 + (t >> 6) * 8 + grp;
    if (ln >= bdiv) return;
    int n = (blockIdx.x & 7) * bdiv + ln;
    if (n >= N) return;
    const float4* h1v = (const float4*)h1;
    float adv = ald[n * 8 + q];
    float acc[16];
#pragma unroll
    for (int k = 0; k < 16; k++) acc[k] = 0.f;
    float wsum = 0.f;
    {  // self loop
        float w = leaky_exp(als[n * 8 + q] + adv);
        wsum += w;
        acc16(w, h1v[(size_t)n * 16 + 2 * q], h1v[(size_t)n * 16 + 2 * q + 1], acc);
    }
    int beg = rowstart[n], end = rowstart[n + 1];
    int j = beg;
    for (; j + 4 <= end; j += 4) {
        int s0 = esrc[j], s1 = esrc[j + 1], s2 = esrc[j + 2], s3 = esrc[j + 3];
        // batch-issue all 12 loads before any use
        float4 a0 = h1v[(size_t)s0 * 16 + 2 * q], b0 = h1v[(size_t)s0 * 16 + 2 * q + 1];
        float4 a1 = h1v[(size_t)s1 * 16 + 2 * q], b1 = h1v[(size_t)s1 * 16 + 2 * q + 1];
        float4 a2 = h1v[(size_t)s2 * 16 + 2 * q], b2 = h1v[(size_t)s2 * 16 + 2 * q + 1];
        float4 a3 = h1v[(size_t)s3 * 16 + 2 * q], b3 = h1v[(size_t)s3 * 16 + 2 * q + 1];
        float e0 = als[s0 * 8 + q], e1 = als[s1 * 8 + q];
        float e2 = als[s2 * 8 + q], e3 = als[s3 * 8 + q];
        float w0 = leaky_exp(e0 + adv), w1 = leaky_exp(e1 + adv);
        float w2 = leaky_exp(e2 + adv), w3 = leaky_exp(e3 + adv);
        wsum += (w0 + w1) + (w2 + w3);
        acc16(w0, a0, b0, acc);
        acc16(w1, a1, b1, acc);
        acc16(w2, a2, b2, acc);
        acc16(w3, a3, b3, acc);
    }
    for (; j < end; j++) {
        int s = esrc[j];
        float w = leaky_exp(als[s * 8 + q] + adv);
        wsum += w;
        acc16(w, h1v[(size_t)s * 16 + 2 * q], h1v[(size_t)s * 16 + 2 * q + 1], acc);
    }
    float inv = 1.f / (wsum + 1e-16f);
    const float* bf = b1 + q * 16;
    __align__(16) __half2 po[8];
#pragma unroll
    for (int k = 0; k < 8; k++) {
        float o0 = acc[2 * k] * inv + bf[2 * k];
        float o1 = acc[2 * k + 1] * inv + bf[2 * k + 1];
        o0 = (o0 > 0.f) ? o0 : (__expf(o0) - 1.f);  // ELU
        o1 = (o1 > 0.f) ? o1 : (__expf(o1) - 1.f);
        po[k] = __floats2half2_rn(o0, o1);
    }
    float4* ov = (float4*)(act1 + (size_t)n * 128 + q * 16);
    ov[0] = ((float4*)po)[0];
    ov[1] = ((float4*)po)[1];
}

// MFMA GEMM2: 64 rows x 80 cols per block; A-frags from global act1 (fp16),
// B-frags from W2t (L1-resident). No LDS.
__global__ __launch_bounds__(256) void gemm2_kernel(const __half* __restrict__ act1,
                                                    const _Float16* __restrict__ W2t,
                                                    __half* __restrict__ h2,
                                                    float* __restrict__ al2s,
                                                    float* __restrict__ al2d, int N) {
    int t = threadIdx.x;
    int row0 = blockIdx.x * 64;
    int w = t >> 6, L = t & 63, m = L & 15, quad = L >> 4;
    f32x4 acc[5];
#pragma unroll
    for (int f = 0; f < 5; f++) acc[f] = (f32x4){0.f, 0.f, 0.f, 0.f};
    const _Float16* Arow =
        (const _Float16*)act1 + (size_t)(row0 + w * 16 + m) * 128 + quad * 8;
    const _Float16* Brow = W2t + m * 128 + quad * 8;
#pragma unroll
    for (int kt = 0; kt < 4; kt++) {
        f16x8 a = *(const f16x8*)(Arow + kt * 32);
#pragma unroll
        for (int f = 0; f < 5; f++) {
            f16x8 b = *(const f16x8*)(Brow + f * 2048 + kt * 32);
            acc[f] = __builtin_amdgcn_mfma_f32_16x16x32_f16(a, b, acc[f], 0, 0, 0);
        }
    }
    int nbase = row0 + w * 16 + quad * 4;
#pragma unroll
    for (int r = 0; r < 4; r++) {
        int n = nbase + r;
        if (n < N) {
            __half* hrow = h2 + (size_t)n * 64 + m;
#pragma unroll
            for (int f = 0; f < 4; f++) hrow[f * 16] = __float2half(acc[f][r]);
            if (m == 0) al2s[n] = acc[4][r];
            else if (m == 1) al2d[n] = acc[4][r];
        }
    }
}

// Aggregation layer 2, node-per-group, XCD-bucketed; lane q owns channels
// 8q..8q+7; edge loop UNROLLED x4 with batched loads.
__global__ __launch_bounds__(256) void agg2_kernel(const __half* __restrict__ h2,
                                                   const float* __restrict__ al2s,
                                                   const float* __restrict__ al2d,
                                                   const int* __restrict__ rowstart,
                                                   const int* __restrict__ esrc,
                                                   const float* __restrict__ b2,
                                                   float* __restrict__ out, int N) {
    int t = threadIdx.x;
    int lane = t & 63;
    int grp = lane >> 3;
    int q = lane & 7;
    int bdiv = (N + 7) >> 3;
    int ln = (blockIdx.x >> 3) * 32 + (t >> 6) * 8 + grp;
    if (ln >= bdiv) return;
    int n = (blockIdx.x & 7) * bdiv + ln;
    if (n >= N) return;
    const float4* h2v = (const float4*)h2;
    float adv = al2d[n];
    float acc[8];
#pragma unroll
    for (int k = 0; k < 8; k++) acc[k] = 0.f;
    float wsum = 0.f;
    {  // self loop
        float w = leaky_exp(al2s[n] + adv);
        wsum += w;
        acc8(w, h2v[(size_t)n * 8 + q], acc);
    }
    int beg = rowstart[n], end = rowstart[n + 1];
    int j = beg;
    for (; j + 4 <= end; j += 4) {
        int s0 = esrc[j], s1 = esrc[j + 1], s2 = esrc[j + 2], s3 = esrc[j + 3];
        float4 a0 = h2v[(size_t)s0 * 8 + q];
        float4 a1 = h2v[(size_t)s1 * 8 + q];
        float4 a2 = h2v[(size_t)s2 * 8 + q];
        float4 a3 = h2v[(size_t)s3 * 8 + q];
        float e0 = al2s[s0], e1 = al2s[s1], e2 = al2s[s2], e3 = al2s[s3];
        float w0 = leaky_exp(e0 + adv), w1 = leaky_exp(e1 + adv);
        float w2 = leaky_exp(e2 + adv), w3 = leaky_exp(e3 + adv);
        wsum += (w0 + w1) + (w2 + w3);
        acc8(w0, a0, acc);
        acc8(w1, a1, acc);
        acc8(w2, a2, acc);
        acc8(w3, a3, acc);
    }
    for (; j < end; j++) {
        int s = esrc[j];
        float w = leaky_exp(al2s[s] + adv);
        wsum += w;
        acc8(w, h2v[(size_t)s * 8 + q], acc);
    }
    float inv = 1.f / (wsum + 1e-16f);
    const float* bf = b2 + q * 8;
    float4* ov = (float4*)(out + (size_t)n * 64 + q * 8);
    ov[0] = make_float4(acc[0] * inv + bf[0], acc[1] * inv + bf[1],
                        acc[2] * inv + bf[2], acc[3] * inv + bf[3]);
    ov[1] = make_float4(acc[4] * inv + bf[4], acc[5] * inv + bf[5],
                        acc[6] * inv + bf[6], acc[7] * inv + bf[7]);
}

extern "C" void kernel_launch(void* const* d_in, const int* in_sizes, int n_in,
                              void* d_out, int out_size, void* d_ws, size_t ws_size,
                              hipStream_t stream) {
    (void)n_in; (void)out_size; (void)ws_size;
    const float* x   = (const float*)d_in[0];
    const int*   ei  = (const int*)d_in[1];
    const float* W1  = (const float*)d_in[2];
    const float* a1s = (const float*)d_in[3];
    const float* a1d = (const float*)d_in[4];
    const float* b1  = (const float*)d_in[5];
    const float* W2  = (const float*)d_in[6];
    const float* a2s = (const float*)d_in[7];
    const float* a2d = (const float*)d_in[8];
    const float* b2  = (const float*)d_in[9];
    float* out = (float*)d_out;

    const int N = in_sizes[0] / 128;
    const int E = in_sizes[1] / 2;
    const int* src = ei;
    const int* dst = ei + E;

    char* wp = (char*)d_ws;
    auto alloc = [&](size_t bytes) -> void* {
        void* p = (void*)wp;
        wp += (bytes + 255) & ~(size_t)255;
        return p;
    };
    __half* h1   = (__half*)alloc((size_t)N * 128 * 2);
    __half* act1 = (__half*)alloc((size_t)N * 128 * 2);
    __half* h2   = (__half*)alloc((size_t)N * 64 * 2 + 64 * 256);  // +pad for gemm2 tail
    float* al1s = (float*)alloc((size_t)N * 8 * 4);
    float* al1d = (float*)alloc((size_t)N * 8 * 4);
    float* al2s = (float*)alloc((size_t)N * 4);
    float* al2d = (float*)alloc((size_t)N * 4);
    int* deg8     = (int*)alloc((size_t)N * 8 * 4);    // 8 XCD-local copies
    int* rowstart = (int*)alloc((size_t)(N + 1) * 4);
    int* cursor   = (int*)alloc((size_t)N * PAD * 4);  // 1 counter / 64B line
    int* esrc     = (int*)alloc((size_t)E * 4);
    int* blocksum = (int*)alloc(256 * 4);
    _Float16* W1t = (_Float16*)alloc(144 * 128 * 2);
    _Float16* W2t = (_Float16*)alloc(80 * 128 * 2);

    const int nbScan = (N + 255) / 256;
    const int gridH  = (E + 1023) / 1024;
    const int gridG1 = (N + 63) / 64;
    const int gridScat = ((E + 1023) / 1024) * 8;
    const int gridG2 = (N + 63) / 64;
    const int bdiv = (N + 7) / 8;
    const int gridAggN = 8 * ((bdiv + 31) / 32);

    hipMemsetAsync(deg8, 0, (size_t)N * 8 * 4, stream);

    augw_kernel<<<2, 256, 0, stream>>>(W1, a1s, a1d, W2, a2s, a2d, W1t, W2t);
    hist_kernel<<<gridH, 256, 0, stream>>>(dst, E, deg8);
    gemm1_kernel<<<gridG1, 256, 0, stream>>>(x, W1t, h1, al1s, al1d, N);
    scan1_kernel<<<nbScan, 256, 0, stream>>>(deg8, N, rowstart, blocksum);
    scan23_kernel<<<(N + 256) / 256, 256, 0, stream>>>(rowstart, blocksum, nbScan,
                                                       cursor, N, E);
    scatter_kernel<<<gridScat, 256, 0, stream>>>(src, dst, E, N, cursor, esrc);

    agg1_kernel<<<gridAggN, 256, 0, stream>>>(h1, al1s, al1d, rowstart, esrc, b1, act1, N);
    gemm2_kernel<<<gridG2, 256, 0, stream>>>(act1, W2t, h2, al2s, al2d, N);
    agg2_kernel<<<gridAggN, 256, 0, stream>>>(h2, al2s, al2d, rowstart, esrc, b2, out, N);
}